// Round 10
// baseline (467.657 us; speedup 1.0000x reference)
//
#include <hip/hip_runtime.h>

// GCN-EEGNet forward, MI355X. Dtype-adaptive (fp32/bf16 detected in K0 via
// adjacency sentinel). Weights in ws, wave-uniform -> SGPR. Intermediates
// f16. Round-22: k23 latency-bound (all pipes <46%, occ 65%, VGPR 20).
// Fix: TILE 1024->512, grid (8, B*C) = 16384 full blocks; LDS 16.6->8.4KB
// so occupancy cap moves to waves (8 blk/CU = 100%); 2x independent
// phase-1 load streams per CU hide L2 latency; barrier domain halves.
// Phase-2 re-parameterized: wave covers 128 t = 4 supertiles; dword base
// q*264 + wv4*64 + m + 2. k4 reverted to r20 uint4/8-half form (r21's
// uint2 4-half was a small regression - 8B/lane streams slower than 16B).
// LESSON (r21): the 6.29M bank conflicts are NOT the ds_swizzle (deleted,
// count unchanged) and not the limiter; don't chase them.
// LESSON (r12): no empty blocks resonant with id%8 XCD rr.
// LESSON (r15): XCD swizzle (c fastest, then t, then b) -> FETCH 66 MB.
// LESSON (r18): per-lane-varying 4B LDS bases conflict; keep lane-uniform
// alignment and consecutive-dword/broadcast patterns.
// Pipeline: K0 -> K0b -> K1 conv1+bn (MFMA) -> 3x K23 -> K4 dw+pool4 ->
// K5 sep -> K6 pool8+fc.

#define B_   32
#define C_   64
#define T_   4000
#define F1_  8
#define TP_  1000
#define W2_  1001
#define MAXDEG 16
#define ROW4 66       // uint4 chunks per i-row staged in LDS (528 halfs)
#define ROWD 264      // dwords per i-row

typedef _Float16 h16x2 __attribute__((ext_vector_type(2)));
typedef _Float16 f16x8 __attribute__((ext_vector_type(8)));
typedef float    f32x4 __attribute__((ext_vector_type(4)));
typedef __fp16   cvt16x2 __attribute__((ext_vector_type(2)));

static __device__ __forceinline__ float bf2f(unsigned short h) {
  union { unsigned int u; float f; } v; v.u = ((unsigned int)h) << 16; return v.f;
}
static __device__ __forceinline__ unsigned short f2bf(float f) {
  union { float f; unsigned int u; } v; v.f = f;
  unsigned int r = v.u + 0x7FFFu + ((v.u >> 16) & 1u);
  return (unsigned short)(r >> 16);
}
static __device__ __forceinline__ float lo_h(unsigned int u) {
  union { unsigned int u; _Float16 h[2]; } v; v.u = u; return (float)v.h[0];
}
static __device__ __forceinline__ unsigned int pack2h(float a, float b) {
  union { _Float16 h[2]; unsigned int u; } v;
  v.h[0] = (_Float16)a; v.h[1] = (_Float16)b; return v.u;
}
#if defined(__has_builtin) && __has_builtin(__builtin_amdgcn_cvt_pkrtz)
static __device__ __forceinline__ unsigned int pkh(float a, float b) {
  union { cvt16x2 h; unsigned int u; } v;
  v.h = __builtin_amdgcn_cvt_pkrtz(a, b);   // v_cvt_pkrtz_f16_f32, 1 instr
  return v.u;
}
#else
static __device__ __forceinline__ unsigned int pkh(float a, float b) {
  return pack2h(a, b);
}
#endif
static __device__ __forceinline__ h16x2 as_h2(unsigned int u) {
  union { unsigned int u; h16x2 h; } v; v.u = u; return v.h;
}
static __device__ __forceinline__ unsigned int alignb(unsigned int hi,
                                                      unsigned int lo,
                                                      unsigned int s) {
  // s in {0,16}; folds to v_alignbit_b32
  return (unsigned int)(((((unsigned long long)hi) << 32) | lo) >> s);
}
// (x.lo16, y.lo16) -> dword:  b0=x.b0 b1=x.b1 b2=y.b0 b3=y.b1
#define PERM_LO(y, x) __builtin_amdgcn_perm((y), (x), 0x05040100u)
// (x.hi16, y.hi16) -> dword
#define PERM_HI(y, x) __builtin_amdgcn_perm((y), (x), 0x07060302u)
#if defined(__has_builtin) && __has_builtin(__builtin_amdgcn_fdot2)
#define DOT2(a, b, c) __builtin_amdgcn_fdot2((a), (b), (c), false)
#else
static __device__ __forceinline__ float dot2_fb(h16x2 a, h16x2 b, float c) {
  return fmaf((float)a[0], (float)b[0], fmaf((float)a[1], (float)b[1], c));
}
#define DOT2(a, b, c) dot2_fb((a), (b), (c))
#endif
static __device__ __forceinline__ float eluf(float z) {
  return z > 0.0f ? z : __expf(z) - 1.0f;
}
static __device__ __forceinline__ float ldin(const void* p, int i, int isf32) {
  return isf32 ? ((const float*)p)[i] : bf2f(((const unsigned short*)p)[i]);
}

// ---------------- K0: dtype detect + canonicalize + CSR + bn fold ----------
__global__ __launch_bounds__(256) void k0_setup(
    const void* __restrict__ adj, const void* __restrict__ imp,
    const void* __restrict__ dww, const void* __restrict__ w1,
    const void* __restrict__ bnF, const void* __restrict__ gw,
    const void* __restrict__ bnsp, const void* __restrict__ sdw,
    const void* __restrict__ pw, const void* __restrict__ bnsep,
    const void* __restrict__ fcw, const void* __restrict__ fcb,
    int* __restrict__ flag, int* __restrict__ deg, int* __restrict__ col,
    uint4* __restrict__ w1mf,
    uint4* __restrict__ wmf, float* __restrict__ dwn,
    float* __restrict__ sdwc, float* __restrict__ pwc,
    float* __restrict__ fcwc, float* __restrict__ fcbc,
    float* __restrict__ bnFs, float* __restrict__ bnsps,
    float* __restrict__ bnseps,
    unsigned int* __restrict__ dwph)   // 16*32 packed f16 weight pairs
{
  __shared__ float dwr[1024];
  __shared__ float dsc[16];
  int tid = threadIdx.x;
  int isf32 = (((const float*)adj)[0] == 1.0f) ? 1 : 0;
  if (tid == 0) *flag = isf32;

  // K1 MFMA B-fragments: cols 8-15 duplicate cols 0-7 (swizzle-free epi).
  for (int idx = tid; idx < 128; idx += 256) {
    int kk = idx >> 6, l = idx & 63;
    int o = l & 7, q = (l >> 4) & 3;
    uint4 v;
    int bi = o*64 + 32*kk + 8*q;
    v.x = pack2h(ldin(w1, bi+0, isf32), ldin(w1, bi+1, isf32));
    v.y = pack2h(ldin(w1, bi+2, isf32), ldin(w1, bi+3, isf32));
    v.z = pack2h(ldin(w1, bi+4, isf32), ldin(w1, bi+5, isf32));
    v.w = pack2h(ldin(w1, bi+6, isf32), ldin(w1, bi+7, isf32));
    w1mf[idx] = v;
  }
  // k23 MFMA B-fragments: cols 8-15 duplicate cols 0-7.
  for (int idx = tid; idx < 384; idx += 256) {
    int lf = idx >> 6;            // layer*2+frag
    int layer = lf >> 1, frag = lf & 1;
    int lane2 = idx & 63;
    int o = lane2 & 7, ii = (lane2 >> 4) + 4*frag;
    uint4 v;
    int bi = layer*512 + (o*8 + ii)*8;
    v.x = pack2h(ldin(gw, bi+0, isf32), ldin(gw, bi+1, isf32));
    v.y = pack2h(ldin(gw, bi+2, isf32), ldin(gw, bi+3, isf32));
    v.z = pack2h(ldin(gw, bi+4, isf32), ldin(gw, bi+5, isf32));
    v.w = pack2h(ldin(gw, bi+6, isf32), ldin(gw, bi+7, isf32));
    wmf[idx] = v;
  }
  for (int i = tid; i < 256;  i += 256) sdwc[i] = ldin(sdw, i, isf32);
  for (int i = tid; i < 256;  i += 256) pwc[i]  = ldin(pw, i, isf32);
  for (int i = tid; i < 8000; i += 256) fcwc[i] = ldin(fcw, i, isf32);
  if (tid < 4) fcbc[tid] = ldin(fcb, tid, isf32);
  for (int i = tid; i < 1024; i += 256) dwr[i] = ldin(dww, i, isf32);

  if (tid < 64) {            // CSR of adjacency (data-driven), self-padded
    int c = tid, n = 0;
    for (int e = 0; e < MAXDEG; ++e) col[c*MAXDEG + e] = c;
    for (int d = 0; d < 64; ++d) {
      if (ldin(adj, c*64 + d, isf32) != 0.0f) {
        if (n < MAXDEG) col[c*MAXDEG + n] = d;
        ++n;
      }
    }
    deg[c] = n < MAXDEG ? n : MAXDEG;
  }
  __syncthreads();
  if (tid < 16) {            // dw norm clamp scale
    float s2 = 0.0f;
    for (int c2 = 0; c2 < 64; ++c2) { float wv = dwr[tid*64 + c2]; s2 += wv*wv; }
    dsc[tid] = fminf(1.0f, 1.0f / fmaxf(sqrtf(s2), 1e-7f));
  }
  if (tid >= 64 && tid < 96) {   // bnF folded scale/shift: 4 stages x 8 ch
    int i = tid - 64, s = i >> 3, f = i & 7;
    float g = ldin(bnF, s*32 + f,      isf32);
    float b = ldin(bnF, s*32 + 8 + f,  isf32);
    float m = ldin(bnF, s*32 + 16 + f, isf32);
    float v = ldin(bnF, s*32 + 24 + f, isf32);
    float sc = g * rsqrtf(v + 1e-3f);
    bnFs[s*16 + f] = sc; bnFs[s*16 + 8 + f] = b - m*sc;
  }
  if (tid >= 96 && tid < 112) {  // bn_sp
    int ch = tid - 96;
    float g = ldin(bnsp, ch, isf32), b = ldin(bnsp, 16 + ch, isf32);
    float m = ldin(bnsp, 32 + ch, isf32), v = ldin(bnsp, 48 + ch, isf32);
    float sc = g * rsqrtf(v + 1e-3f);
    bnsps[ch] = sc; bnsps[16 + ch] = b - m*sc;
  }
  if (tid >= 112 && tid < 128) { // bn_sep
    int ch = tid - 112;
    float g = ldin(bnsep, ch, isf32), b = ldin(bnsep, 16 + ch, isf32);
    float m = ldin(bnsep, 32 + ch, isf32), v = ldin(bnsep, 48 + ch, isf32);
    float sc = g * rsqrtf(v + 1e-3f);
    bnseps[ch] = sc; bnseps[16 + ch] = b - m*sc;
  }
  __syncthreads();
  for (int i = tid; i < 1024; i += 256) dwn[i] = dwr[i] * dsc[i >> 6];
  __syncthreads();
  // packed f16 dw-weight pairs (from shared dwr*dsc, no global dep)
  for (int idx = tid; idx < 512; idx += 256) {
    int ch = idx >> 5, p = idx & 31;
    dwph[idx] = pack2h(dwr[ch*64 + 2*p]   * dsc[ch],
                       dwr[ch*64 + 2*p+1] * dsc[ch]);
  }
}

// ---------------- K0b: avals + avph (parallel over 1536 combos) -----------
__global__ __launch_bounds__(256) void k0b_avals(
    const void* __restrict__ adj, const void* __restrict__ imp,
    const int* __restrict__ flag,
    const int* __restrict__ deg, const int* __restrict__ col,
    float* __restrict__ avals, unsigned int* __restrict__ avph)
{
  int combo = blockIdx.x * 256 + threadIdx.x;   // < 1536
  int isf32 = *flag;
  int c = combo & 63;
  int lf = combo >> 6;                 // l*8+f
  int dg = deg[c];
  float av[MAXDEG];
  for (int e = 0; e < MAXDEG; ++e) {
    float v = 0.0f;
    if (e < dg) {
      int d = col[c*MAXDEG + e];
      v = ldin(adj, c*64 + d, isf32) * ldin(imp, (lf*64 + c)*64 + d, isf32);
    }
    av[e] = v;
    avals[combo*MAXDEG + e] = v;
  }
  for (int p = 0; p < 8; ++p)
    avph[combo*8 + p] = pack2h(av[2*p], av[2*p + 1]);
}

// ---------------- K1: conv1 (64-tap) via MFMA + bn0 ------------------------
// grid (4 t-tiles of 1024, B*C). Stride-2 supertiles, duplicated B cols.
__global__ __launch_bounds__(256, 4) void k1_conv1_bn(
    const void* __restrict__ x,               // B,C,T raw dtype
    const uint4* __restrict__ w1mf,           // 2*64 B-fragments
    const float* __restrict__ bnFs,
    const int* __restrict__ flag,
    unsigned short* __restrict__ outp)        // B,F1,C,T f16
{
  __shared__ __align__(16) unsigned int xs[548];   // 1096 halfs
  int tid = threadIdx.x;
  int bc = blockIdx.y;                 // b*64+c
  int b = bc >> 6, c = bc & 63;
  int tb = blockIdx.x * 1024;
  int isf32 = *flag;
  int row = bc * T_;
  if (isf32) {
    const float* xr = (const float*)x + row;
    for (int m = tid; m < 274; m += 256) {
      int tg = tb - 36 + 4*m;
      uint2 st;
      if (tg >= 0 && tg + 3 < T_) {
        float4 v = *(const float4*)(xr + tg);               // 16B aligned
        st.x = pkh(v.x, v.y); st.y = pkh(v.z, v.w);
      } else {
        float q0 = (tg   >= 0 && tg   < T_) ? xr[tg]   : 0.0f;
        float q1 = (tg+1 >= 0 && tg+1 < T_) ? xr[tg+1] : 0.0f;
        float q2 = (tg+2 >= 0 && tg+2 < T_) ? xr[tg+2] : 0.0f;
        float q3 = (tg+3 >= 0 && tg+3 < T_) ? xr[tg+3] : 0.0f;
        st.x = pkh(q0, q1); st.y = pkh(q2, q3);
      }
      *(uint2*)(xs + 2*m) = st;
    }
  } else {
    const unsigned short* xr = (const unsigned short*)x + row;
    for (int m = tid; m < 274; m += 256) {
      int tg = tb - 36 + 4*m;
      uint2 st;
      if (tg >= 0 && tg + 3 < T_) {
        uint2 v = *(const uint2*)(xr + tg);                 // 8B aligned
        st.x = pkh(bf2f((unsigned short)(v.x & 0xFFFFu)),
                   bf2f((unsigned short)(v.x >> 16)));
        st.y = pkh(bf2f((unsigned short)(v.y & 0xFFFFu)),
                   bf2f((unsigned short)(v.y >> 16)));
      } else {
        float q0 = (tg   >= 0 && tg   < T_) ? bf2f(xr[tg])   : 0.0f;
        float q1 = (tg+1 >= 0 && tg+1 < T_) ? bf2f(xr[tg+1]) : 0.0f;
        float q2 = (tg+2 >= 0 && tg+2 < T_) ? bf2f(xr[tg+2]) : 0.0f;
        float q3 = (tg+3 >= 0 && tg+3 < T_) ? bf2f(xr[tg+3]) : 0.0f;
        st.x = pkh(q0, q1); st.y = pkh(q2, q3);
      }
      *(uint2*)(xs + 2*m) = st;
    }
  }
  __syncthreads();

  int lane = tid & 63;
  int wv4 = tid >> 6;                  // wave 0..3
  int m = lane & 15, q = lane >> 4;
  int sel = (m >> 3) & 1;              // 0: t+0..3, 1: t+4..7
  union { uint4 u; f16x8 h; } w0u, w1u;
  w0u.u = w1mf[lane];
  w1u.u = w1mf[64 + lane];
  int o8 = m & 7;
  float sc  = bnFs[o8];
  float shb = bnFs[8 + o8];
  const unsigned int* p0 = xs + 2 + m + 4*q + 128*wv4;
  unsigned short* orow = outp + (size_t)((b*8 + o8)*64 + c) * T_;
  #pragma unroll
  for (int s = 0; s < 8; ++s) {
    unsigned dwa[5], dwb[5];
    #pragma unroll
    for (int j = 0; j < 5; ++j) {
      dwa[j] = p0[16*s + j];           // kk=0 window
      dwb[j] = p0[16*s + 16 + j];      // kk=1 window (== s+1 kk=0: CSE)
    }
    union { unsigned d[4]; f16x8 h; } Ae0, Ao0, Ae1, Ao1;
    #pragma unroll
    for (int j = 0; j < 4; ++j) {
      Ao0.d[j] = dwa[j+1];                       // odd rows: pure copy
      Ae0.d[j] = alignb(dwa[j+1], dwa[j], 16);   // even rows: const shift
      Ao1.d[j] = dwb[j+1];
      Ae1.d[j] = alignb(dwb[j+1], dwb[j], 16);
    }
    f32x4 ae = {0.0f, 0.0f, 0.0f, 0.0f};
    f32x4 ao = {0.0f, 0.0f, 0.0f, 0.0f};
    ae = __builtin_amdgcn_mfma_f32_16x16x32_f16(Ae0.h, w0u.h, ae, 0, 0, 0);
    ae = __builtin_amdgcn_mfma_f32_16x16x32_f16(Ae1.h, w1u.h, ae, 0, 0, 0);
    ao = __builtin_amdgcn_mfma_f32_16x16x32_f16(Ao0.h, w0u.h, ao, 0, 0, 0);
    ao = __builtin_amdgcn_mfma_f32_16x16x32_f16(Ao1.h, w1u.h, ao, 0, 0, 0);
    // B cols duplicated: lane m>=8 owns D rows 4q+2,3 locally
    float y0 = sel ? ae[2] : ae[0];
    float y1 = sel ? ao[2] : ao[0];
    float y2 = sel ? ae[3] : ae[1];
    float y3 = sel ? ao[3] : ao[1];
    int t0g = tb + wv4*256 + s*32 + 8*q + 4*sel;
    if (t0g < T_) {
      uint2 st;
      st.x = pkh(y0*sc + shb, y1*sc + shb);
      st.y = pkh(y2*sc + shb, y3*sc + shb);
      *(uint2*)(orow + t0g) = st;
    }
  }
}

// ---------------- K23: fused graph einsum + MFMA gconv + bn + elu ----------
// grid (8, B*C) = 16384 full blocks, TILE=512. XCD swizzle (c fastest,
// xt, b). Phase 1: 32 threads/i-row stage Ah into 8.4 KB LDS (edge-pair
// dot2, avph). Phase 2: 4 stride-2 supertiles/wave; dword base
// q*264 + wv4*64 + m + 2; duplicated B cols -> swizzle-free epilogue.
__global__ __launch_bounds__(256, 8) void k23_gcn_gconv(
    const unsigned short* __restrict__ in,    // B,F1,C,T f16
    unsigned short* __restrict__ outp,        // B,F1,C,T f16
    const int* __restrict__ deg, const int* __restrict__ col,
    const float* __restrict__ avals,          // 3*8*64*MAXDEG (boundary path)
    const unsigned int* __restrict__ avph,    // 3*8*64*8 packed pairs
    const uint4* __restrict__ wmf,            // 6*64 B-fragments
    const float* __restrict__ bnFs, int l)
{
  __shared__ __align__(16) uint4 ash[8 * ROW4];   // 8,448 B
  int tid = threadIdx.x;
  // bijective XCD swizzle (16384 blocks, 8 XCDs)
  int wgid = blockIdx.y * 8 + blockIdx.x;
  int swz  = (wgid & 7) * 2048 + (wgid >> 3);
  int c = swz & 63;
  int xt = (swz >> 6) & 7;
  int b = swz >> 9;
  int tb = xt * 512;
  int wb = tb - 8;                     // staged range [wb, wb+528)
  int dg = deg[c];                     // uniform -> s_load
  const int* cp = col + c*MAXDEG;

  // ---- phase 1: stage Ah into LDS, 32 threads per i-row ----
  {
    int i = tid >> 5;                  // 0..7
    int mlane = tid & 31;
    int dgp = (dg + 1) >> 1;
    const unsigned int* wpp = avph + ((l*8 + i)*64 + c) * 8;   // uniform
    const float* av = avals + ((l*8 + i)*64 + c) * MAXDEG;     // uniform
    const unsigned short* rbp = in + (size_t)((b*8 + i) * 64) * T_;
    for (int m = mlane; m < ROW4; m += 32) {
      int t = wb + 8*m;
      float a[8] = {0,0,0,0,0,0,0,0};
      if (t >= 0 && t + 7 < T_) {
        for (int p = 0; p < dgp; ++p) {
          int d0 = cp[2*p];            // uniform -> s_load
          int d1 = cp[2*p + 1];
          h16x2 w2 = as_h2(wpp[p]);    // uniform
          uint4 v0 = *(const uint4*)(rbp + d0*T_ + t);   // 16B aligned
          uint4 v1 = *(const uint4*)(rbp + d1*T_ + t);
          a[0] = DOT2(as_h2(PERM_LO(v1.x, v0.x)), w2, a[0]);
          a[1] = DOT2(as_h2(PERM_HI(v1.x, v0.x)), w2, a[1]);
          a[2] = DOT2(as_h2(PERM_LO(v1.y, v0.y)), w2, a[2]);
          a[3] = DOT2(as_h2(PERM_HI(v1.y, v0.y)), w2, a[3]);
          a[4] = DOT2(as_h2(PERM_LO(v1.z, v0.z)), w2, a[4]);
          a[5] = DOT2(as_h2(PERM_HI(v1.z, v0.z)), w2, a[5]);
          a[6] = DOT2(as_h2(PERM_LO(v1.w, v0.w)), w2, a[6]);
          a[7] = DOT2(as_h2(PERM_HI(v1.w, v0.w)), w2, a[7]);
        }
      } else if (t + 7 >= 0 && t < T_) {
        for (int e = 0; e < dg; ++e) {
          int d = cp[e];
          float wv = av[e];
          const unsigned short* rp = rbp + d*T_;
          #pragma unroll
          for (int q = 0; q < 8; ++q) {
            int tq = t + q;
            if (tq >= 0 && tq < T_)
              a[q] = fmaf(wv, lo_h((unsigned int)rp[tq]), a[q]);
          }
        }
      }
      uint4 o;
      o.x = pkh(a[0], a[1]); o.y = pkh(a[2], a[3]);
      o.z = pkh(a[4], a[5]); o.w = pkh(a[6], a[7]);
      ash[i*ROW4 + m] = o;
    }
  }
  __syncthreads();

  // ---- phase 2: MFMA gconv, 4 stride-2 supertiles/wave ----
  int lane = tid & 63;
  int wv4 = tid >> 6;                  // wave 0..3
  int m = lane & 15, q = lane >> 4;
  int sel = (m >> 3) & 1;              // 0: t+0..3, 1: t+4..7
  union { uint4 u; f16x8 h; } w0u, w1u;
  w0u.u = wmf[(l*2 + 0)*64 + lane];
  w1u.u = wmf[(l*2 + 1)*64 + lane];
  int o8 = m & 7;
  float sc  = bnFs[(l+1)*16 + o8];
  float shb = bnFs[(l+1)*16 + 8 + o8];
  const unsigned int* ashd = (const unsigned int*)ash;
  const unsigned int* p0 = ashd + q*ROWD + wv4*64 + m + 2;   // dword idx
  const unsigned int* p1 = p0 + 4*ROWD;
  unsigned short* orow = outp + (size_t)((b*8 + o8)*64 + c) * T_;
  #pragma unroll
  for (int s = 0; s < 4; ++s) {
    unsigned dwa[5], dwb[5];
    #pragma unroll
    for (int j = 0; j < 5; ++j) {      // immediate-offset ds_read2_b32
      dwa[j] = p0[16*s + j];
      dwb[j] = p1[16*s + j];
    }
    union { unsigned d[4]; f16x8 h; } Ae0, Ao0, Ae1, Ao1;
    #pragma unroll
    for (int j = 0; j < 4; ++j) {
      Ao0.d[j] = dwa[j+1];                       // odd rows: pure copy
      Ae0.d[j] = alignb(dwa[j+1], dwa[j], 16);   // even rows: const shift
      Ao1.d[j] = dwb[j+1];
      Ae1.d[j] = alignb(dwb[j+1], dwb[j], 16);
    }
    f32x4 ae = {0.0f, 0.0f, 0.0f, 0.0f};
    f32x4 ao = {0.0f, 0.0f, 0.0f, 0.0f};
    ae = __builtin_amdgcn_mfma_f32_16x16x32_f16(Ae0.h, w0u.h, ae, 0, 0, 0);
    ae = __builtin_amdgcn_mfma_f32_16x16x32_f16(Ae1.h, w1u.h, ae, 0, 0, 0);
    ao = __builtin_amdgcn_mfma_f32_16x16x32_f16(Ao0.h, w0u.h, ao, 0, 0, 0);
    ao = __builtin_amdgcn_mfma_f32_16x16x32_f16(Ao1.h, w1u.h, ao, 0, 0, 0);
    // B cols duplicated: lane m>=8 owns D rows 4q+2,3 locally
    float y0 = sel ? ae[2] : ae[0];
    float y1 = sel ? ao[2] : ao[0];
    float y2 = sel ? ae[3] : ae[1];
    float y3 = sel ? ao[3] : ao[1];
    int t0g = tb + wv4*128 + s*32 + 8*q + 4*sel;
    if (t0g < T_) {
      uint2 st;
      st.x = pkh(eluf(y0*sc + shb), eluf(y1*sc + shb));
      st.y = pkh(eluf(y2*sc + shb), eluf(y3*sc + shb));
      *(uint2*)(orow + t0g) = st;
    }
  }
}

// ---------------- K4: depthwise-over-C + bn + elu + avgpool4. 8 t/thread ---
// cc-pair dot2: (h_cc0[t],h_cc1[t]) via v_perm, weight pairs dwph (SGPR).
__global__ __launch_bounds__(256) void k4_dw(
    const unsigned short* __restrict__ in,    // B,F1,C,T f16
    const unsigned int* __restrict__ dwph,    // 16x32 packed f16 pairs
    const float* __restrict__ bnsps,
    float* __restrict__ p1)                   // B,16,1000 fp32
{
  int tid = threadIdx.x;
  int bg = blockIdx.y;                 // b*8+g
  int b = bg >> 3, g = bg & 7;
  int tile = blockIdx.x * 256 + tid;
  if (tile >= 500) return;
  int t0 = tile * 8;
  int base = bg * (64 * T_);
  const unsigned int* w0pp = dwph + (2*g)*32;      // uniform -> s_load
  const unsigned int* w1pp = dwph + (2*g + 1)*32;
  float a0[8] = {0,0,0,0,0,0,0,0}, a1[8] = {0,0,0,0,0,0,0,0};
  for (int p = 0; p < 32; ++p) {
    h16x2 w02 = as_h2(w0pp[p]);        // uniform
    h16x2 w12 = as_h2(w1pp[p]);        // uniform
    uint4 v0 = *(const uint4*)(in + base + (2*p)*T_ + t0);
    uint4 v1 = *(const uint4*)(in + base + (2*p + 1)*T_ + t0);
    unsigned pr;
    pr = PERM_LO(v1.x, v0.x);
    a0[0] = DOT2(as_h2(pr), w02, a0[0]); a1[0] = DOT2(as_h2(pr), w12, a1[0]);
    pr = PERM_HI(v1.x, v0.x);
    a0[1] = DOT2(as_h2(pr), w02, a0[1]); a1[1] = DOT2(as_h2(pr), w12, a1[1]);
    pr = PERM_LO(v1.y, v0.y);
    a0[2] = DOT2(as_h2(pr), w02, a0[2]); a1[2] = DOT2(as_h2(pr), w12, a1[2]);
    pr = PERM_HI(v1.y, v0.y);
    a0[3] = DOT2(as_h2(pr), w02, a0[3]); a1[3] = DOT2(as_h2(pr), w12, a1[3]);
    pr = PERM_LO(v1.z, v0.z);
    a0[4] = DOT2(as_h2(pr), w02, a0[4]); a1[4] = DOT2(as_h2(pr), w12, a1[4]);
    pr = PERM_HI(v1.z, v0.z);
    a0[5] = DOT2(as_h2(pr), w02, a0[5]); a1[5] = DOT2(as_h2(pr), w12, a1[5]);
    pr = PERM_LO(v1.w, v0.w);
    a0[6] = DOT2(as_h2(pr), w02, a0[6]); a1[6] = DOT2(as_h2(pr), w12, a1[6]);
    pr = PERM_HI(v1.w, v0.w);
    a0[7] = DOT2(as_h2(pr), w02, a0[7]); a1[7] = DOT2(as_h2(pr), w12, a1[7]);
  }
  float sc0 = bnsps[2*g],     sh0 = bnsps[16 + 2*g];
  float sc1 = bnsps[2*g + 1], sh1 = bnsps[16 + 2*g + 1];
  int oi = t0 >> 2;
  float2 r0, r1;
  r0.x = 0.25f * (eluf(a0[0]*sc0+sh0) + eluf(a0[1]*sc0+sh0)
                + eluf(a0[2]*sc0+sh0) + eluf(a0[3]*sc0+sh0));
  r0.y = 0.25f * (eluf(a0[4]*sc0+sh0) + eluf(a0[5]*sc0+sh0)
                + eluf(a0[6]*sc0+sh0) + eluf(a0[7]*sc0+sh0));
  r1.x = 0.25f * (eluf(a1[0]*sc1+sh1) + eluf(a1[1]*sc1+sh1)
                + eluf(a1[2]*sc1+sh1) + eluf(a1[3]*sc1+sh1));
  r1.y = 0.25f * (eluf(a1[4]*sc1+sh1) + eluf(a1[5]*sc1+sh1)
                + eluf(a1[6]*sc1+sh1) + eluf(a1[7]*sc1+sh1));
  *(float2*)(p1 + (b*16 + 2*g)*TP_ + oi)     = r0;
  *(float2*)(p1 + (b*16 + 2*g + 1)*TP_ + oi) = r1;
}

// ---------------- K5: sep depthwise(16) + pointwise(16x16) + bn + elu ------
__global__ __launch_bounds__(256) void k5_sep(
    const float* __restrict__ p1,             // B,16,1000
    const float* __restrict__ sdwc,           // 16x16 (uniform)
    const float* __restrict__ pwc,            // 16x16 (uniform)
    const float* __restrict__ bnseps,
    float* __restrict__ p2)                   // B,16,1001
{
  __shared__ float ps[16*272];
  int tid = threadIdx.x;
  int wq = blockIdx.x, b = blockIdx.y;
  int wb = wq * 256;
  for (int ch = 0; ch < 16; ++ch) {
    for (int s = tid; s < 272; s += 256) {
      int t = wb - 8 + s;
      ps[ch*272 + s] = (t >= 0 && t < TP_) ? p1[(b*16 + ch)*TP_ + t] : 0.0f;
    }
  }
  __syncthreads();
  int w0 = wb + tid;
  if (w0 >= W2_) return;
  float dws[16];
  for (int ch = 0; ch < 16; ++ch) {
    float a = 0.0f;
    #pragma unroll
    for (int k = 0; k < 16; ++k)
      a = fmaf(sdwc[ch*16 + k], ps[ch*272 + tid + k], a);
    dws[ch] = a;
  }
  for (int f = 0; f < 16; ++f) {
    float a = 0.0f;
    #pragma unroll
    for (int ch = 0; ch < 16; ++ch) a = fmaf(pwc[f*16 + ch], dws[ch], a);
    float sc = bnseps[f], sh = bnseps[16 + f];
    p2[(b*16 + f)*W2_ + w0] = eluf(a*sc + sh);
  }
}

// ---------------- K6: avgpool8 (first 1000) + fc ---------------------------
__global__ __launch_bounds__(256) void k6_fc(
    const float* __restrict__ p2,             // B,16,1001
    const float* __restrict__ fcwc,           // 4x2000
    const float* __restrict__ fcbc,           // 4
    const int* __restrict__ flag,
    void* __restrict__ outp)                  // B,4
{
  __shared__ float red[4*256];
  int tid = threadIdx.x;
  int b = blockIdx.x;
  float part[4] = {0.0f, 0.0f, 0.0f, 0.0f};
  for (int idx = tid; idx < 2000; idx += 256) {
    int f = idx / 125, q = idx - f*125;
    const float* src = p2 + (b*16 + f)*W2_ + q*8;
    float s = src[0]+src[1]+src[2]+src[3]+src[4]+src[5]+src[6]+src[7];
    float mval = 0.125f * s;
    #pragma unroll
    for (int n = 0; n < 4; ++n) part[n] = fmaf(fcwc[n*2000 + idx], mval, part[n]);
  }
  #pragma unroll
  for (int n = 0; n < 4; ++n) red[n*256 + tid] = part[n];
  __syncthreads();
  for (int s = 128; s > 0; s >>= 1) {
    if (tid < s) {
      #pragma unroll
      for (int n = 0; n < 4; ++n) red[n*256 + tid] += red[n*256 + tid + s];
    }
    __syncthreads();
  }
  if (tid < 4) {
    float val = red[tid*256] + fcbc[tid];
    if (*flag) ((float*)outp)[b*4 + tid] = val;
    else       ((unsigned short*)outp)[b*4 + tid] = f2bf(val);
  }
}

// ---------------------------------------------------------------------------
extern "C" void kernel_launch(void* const* d_in, const int* in_sizes, int n_in,
                              void* d_out, int out_size, void* d_ws, size_t ws_size,
                              hipStream_t stream) {
  const void* x     = d_in[0];
  const void* adj   = d_in[1];
  const void* w1    = d_in[2];
  const void* bnF   = d_in[3];
  const void* imp   = d_in[4];
  const void* gw    = d_in[5];
  const void* dww   = d_in[6];
  const void* bnsp  = d_in[7];
  const void* sdw   = d_in[8];
  const void* pw    = d_in[9];
  const void* bnsep = d_in[10];
  const void* fcw   = d_in[11];
  const void* fcb   = d_in[12];

  char* w = (char*)d_ws;
  const size_t OFF = 262144000;  // after two 131,072,000-byte f16 buffers
  unsigned short* bufA = (unsigned short*)(w);
  unsigned short* bufB = (unsigned short*)(w + 131072000);
  int*   flag   = (int*)  (w + OFF + 0);
  int*   deg    = (int*)  (w + OFF + 256);
  int*   col    = (int*)  (w + OFF + 512);
  float* avals  = (float*)(w + OFF + 4608);
  float* dwn    = (float*)(w + OFF + 108032);
  float* sdwc   = (float*)(w + OFF + 112128);
  float* pwc    = (float*)(w + OFF + 113152);
  float* fcwc   = (float*)(w + OFF + 114176);
  float* fcbc   = (float*)(w + OFF + 146176);
  float* bnFs   = (float*)(w + OFF + 146432);
  float* bnsps  = (float*)(w + OFF + 146688);
  float* bnseps = (float*)(w + OFF + 146944);
  float* p1     = (float*)(w + OFF + 147200);
  float* p2     = (float*)(w + OFF + 2195200);
  uint4* wmf    = (uint4*)(w + OFF + 4245248);              // 384 uint4
  unsigned int* avph = (unsigned int*)(w + OFF + 4251392);  // 12288 uints
  unsigned int* dwph = (unsigned int*)(w + OFF + 4300544);  // 512 uints
  uint4* w1mf   = (uint4*)(w + OFF + 4302592);              // 128 uint4

  k0_setup<<<1, 256, 0, stream>>>(adj, imp, dww, w1, bnF, gw, bnsp, sdw, pw,
                                  bnsep, fcw, fcb, flag, deg, col,
                                  w1mf, wmf, dwn, sdwc, pwc, fcwc, fcbc,
                                  bnFs, bnsps, bnseps, dwph);
  k0b_avals<<<6, 256, 0, stream>>>(adj, imp, flag, deg, col, avals, avph);
  k1_conv1_bn<<<dim3(4, B_*C_), 256, 0, stream>>>(x, w1mf, bnFs, flag, bufA);
  for (int l = 0; l < 3; ++l) {
    const unsigned short* src = (l & 1) ? bufB : bufA;
    unsigned short*       dst = (l & 1) ? bufA : bufB;
    k23_gcn_gconv<<<dim3(8, B_*C_), 256, 0, stream>>>(src, dst, deg, col,
                                                      avals, avph, wmf, bnFs, l);
  }
  k4_dw<<<dim3(2, B_*F1_), 256, 0, stream>>>(bufB, dwph, bnsps, p1);
  k5_sep<<<dim3(4, B_), 256, 0, stream>>>(p1, sdwc, pwc, bnseps, p2);
  k6_fc<<<32, 256, 0, stream>>>(p2, fcwc, fcbc, flag, d_out);
}

// Round 11
// 452.464 us; speedup vs baseline: 1.0336x; 1.0336x over previous
//
#include <hip/hip_runtime.h>

// GCN-EEGNet forward, MI355X. Dtype-adaptive (fp32/bf16 detected in K0 via
// adjacency sentinel). Weights in ws, wave-uniform -> SGPR. Intermediates
// f16. Round-23: (a) k23 reverted to TILE=1024 (r22's TILE=512 regressed:
// occupancy 65->71 only, +2us/layer — the cap is not LDS/tile; ~95us is
// this structure's plateau). (b) K5+K6 fused: p2 never hits HBM; k5
// blocks pool-8 their own 256-w window (32 aligned groups), compute fc
// partials (feature = ch*125 + j), block-reduce, 4 atomicAdds into f32
// fcacc (zeroed in K0); K6c = 1-block bias+convert. Saves p2 round trip,
// k6's 32x2000 reductions, one launch.
// LESSON (r22): k23 TILE=512 regressed; occupancy cap isn't tile size.
// LESSON (r21): the 6.29M bank conflicts are NOT the limiter.
// LESSON (r12): no empty blocks resonant with id%8 XCD rr.
// LESSON (r15): XCD swizzle (c fastest, then t, then b) -> FETCH 66 MB.
// LESSON (r18): per-lane-varying 4B LDS bases conflict; keep lane-uniform
// alignment and consecutive-dword/broadcast patterns.
// Pipeline: K0 -> K0b -> K1 conv1+bn (MFMA) -> 3x K23 -> K4 dw+pool4 ->
// K5 sep+fc-partial -> K6c bias+convert.

#define B_   32
#define C_   64
#define T_   4000
#define F1_  8
#define TP_  1000
#define W2_  1001
#define MAXDEG 16
#define ROW4 130      // uint4 chunks per i-row staged in LDS (1040 halfs)
#define ROWD 520      // dwords per i-row

typedef _Float16 h16x2 __attribute__((ext_vector_type(2)));
typedef _Float16 f16x8 __attribute__((ext_vector_type(8)));
typedef float    f32x4 __attribute__((ext_vector_type(4)));
typedef __fp16   cvt16x2 __attribute__((ext_vector_type(2)));

static __device__ __forceinline__ float bf2f(unsigned short h) {
  union { unsigned int u; float f; } v; v.u = ((unsigned int)h) << 16; return v.f;
}
static __device__ __forceinline__ unsigned short f2bf(float f) {
  union { float f; unsigned int u; } v; v.f = f;
  unsigned int r = v.u + 0x7FFFu + ((v.u >> 16) & 1u);
  return (unsigned short)(r >> 16);
}
static __device__ __forceinline__ float lo_h(unsigned int u) {
  union { unsigned int u; _Float16 h[2]; } v; v.u = u; return (float)v.h[0];
}
static __device__ __forceinline__ unsigned int pack2h(float a, float b) {
  union { _Float16 h[2]; unsigned int u; } v;
  v.h[0] = (_Float16)a; v.h[1] = (_Float16)b; return v.u;
}
#if defined(__has_builtin) && __has_builtin(__builtin_amdgcn_cvt_pkrtz)
static __device__ __forceinline__ unsigned int pkh(float a, float b) {
  union { cvt16x2 h; unsigned int u; } v;
  v.h = __builtin_amdgcn_cvt_pkrtz(a, b);   // v_cvt_pkrtz_f16_f32, 1 instr
  return v.u;
}
#else
static __device__ __forceinline__ unsigned int pkh(float a, float b) {
  return pack2h(a, b);
}
#endif
static __device__ __forceinline__ h16x2 as_h2(unsigned int u) {
  union { unsigned int u; h16x2 h; } v; v.u = u; return v.h;
}
static __device__ __forceinline__ unsigned int alignb(unsigned int hi,
                                                      unsigned int lo,
                                                      unsigned int s) {
  // s in {0,16}; folds to v_alignbit_b32
  return (unsigned int)(((((unsigned long long)hi) << 32) | lo) >> s);
}
// (x.lo16, y.lo16) -> dword:  b0=x.b0 b1=x.b1 b2=y.b0 b3=y.b1
#define PERM_LO(y, x) __builtin_amdgcn_perm((y), (x), 0x05040100u)
// (x.hi16, y.hi16) -> dword
#define PERM_HI(y, x) __builtin_amdgcn_perm((y), (x), 0x07060302u)
#if defined(__has_builtin) && __has_builtin(__builtin_amdgcn_fdot2)
#define DOT2(a, b, c) __builtin_amdgcn_fdot2((a), (b), (c), false)
#else
static __device__ __forceinline__ float dot2_fb(h16x2 a, h16x2 b, float c) {
  return fmaf((float)a[0], (float)b[0], fmaf((float)a[1], (float)b[1], c));
}
#define DOT2(a, b, c) dot2_fb((a), (b), (c))
#endif
static __device__ __forceinline__ float eluf(float z) {
  return z > 0.0f ? z : __expf(z) - 1.0f;
}
static __device__ __forceinline__ float ldin(const void* p, int i, int isf32) {
  return isf32 ? ((const float*)p)[i] : bf2f(((const unsigned short*)p)[i]);
}

// ---------------- K0: dtype detect + canonicalize + CSR + bn fold ----------
__global__ __launch_bounds__(256) void k0_setup(
    const void* __restrict__ adj, const void* __restrict__ imp,
    const void* __restrict__ dww, const void* __restrict__ w1,
    const void* __restrict__ bnF, const void* __restrict__ gw,
    const void* __restrict__ bnsp, const void* __restrict__ sdw,
    const void* __restrict__ pw, const void* __restrict__ bnsep,
    const void* __restrict__ fcw, const void* __restrict__ fcb,
    int* __restrict__ flag, int* __restrict__ deg, int* __restrict__ col,
    uint4* __restrict__ w1mf,
    uint4* __restrict__ wmf, float* __restrict__ dwn,
    float* __restrict__ sdwc, float* __restrict__ pwc,
    float* __restrict__ fcwc, float* __restrict__ fcbc,
    float* __restrict__ bnFs, float* __restrict__ bnsps,
    float* __restrict__ bnseps,
    unsigned int* __restrict__ dwph,   // 16*32 packed f16 weight pairs
    float* __restrict__ fcacc)         // B*4 f32 accumulator (zeroed)
{
  __shared__ float dwr[1024];
  __shared__ float dsc[16];
  int tid = threadIdx.x;
  int isf32 = (((const float*)adj)[0] == 1.0f) ? 1 : 0;
  if (tid == 0) *flag = isf32;
  if (tid < 128) fcacc[tid] = 0.0f;

  // K1 MFMA B-fragments: cols 8-15 duplicate cols 0-7 (swizzle-free epi).
  for (int idx = tid; idx < 128; idx += 256) {
    int kk = idx >> 6, l = idx & 63;
    int o = l & 7, q = (l >> 4) & 3;
    uint4 v;
    int bi = o*64 + 32*kk + 8*q;
    v.x = pack2h(ldin(w1, bi+0, isf32), ldin(w1, bi+1, isf32));
    v.y = pack2h(ldin(w1, bi+2, isf32), ldin(w1, bi+3, isf32));
    v.z = pack2h(ldin(w1, bi+4, isf32), ldin(w1, bi+5, isf32));
    v.w = pack2h(ldin(w1, bi+6, isf32), ldin(w1, bi+7, isf32));
    w1mf[idx] = v;
  }
  // k23 MFMA B-fragments: cols 8-15 duplicate cols 0-7.
  for (int idx = tid; idx < 384; idx += 256) {
    int lf = idx >> 6;            // layer*2+frag
    int layer = lf >> 1, frag = lf & 1;
    int lane2 = idx & 63;
    int o = lane2 & 7, ii = (lane2 >> 4) + 4*frag;
    uint4 v;
    int bi = layer*512 + (o*8 + ii)*8;
    v.x = pack2h(ldin(gw, bi+0, isf32), ldin(gw, bi+1, isf32));
    v.y = pack2h(ldin(gw, bi+2, isf32), ldin(gw, bi+3, isf32));
    v.z = pack2h(ldin(gw, bi+4, isf32), ldin(gw, bi+5, isf32));
    v.w = pack2h(ldin(gw, bi+6, isf32), ldin(gw, bi+7, isf32));
    wmf[idx] = v;
  }
  for (int i = tid; i < 256;  i += 256) sdwc[i] = ldin(sdw, i, isf32);
  for (int i = tid; i < 256;  i += 256) pwc[i]  = ldin(pw, i, isf32);
  for (int i = tid; i < 8000; i += 256) fcwc[i] = ldin(fcw, i, isf32);
  if (tid < 4) fcbc[tid] = ldin(fcb, tid, isf32);
  for (int i = tid; i < 1024; i += 256) dwr[i] = ldin(dww, i, isf32);

  if (tid < 64) {            // CSR of adjacency (data-driven), self-padded
    int c = tid, n = 0;
    for (int e = 0; e < MAXDEG; ++e) col[c*MAXDEG + e] = c;
    for (int d = 0; d < 64; ++d) {
      if (ldin(adj, c*64 + d, isf32) != 0.0f) {
        if (n < MAXDEG) col[c*MAXDEG + n] = d;
        ++n;
      }
    }
    deg[c] = n < MAXDEG ? n : MAXDEG;
  }
  __syncthreads();
  if (tid < 16) {            // dw norm clamp scale
    float s2 = 0.0f;
    for (int c2 = 0; c2 < 64; ++c2) { float wv = dwr[tid*64 + c2]; s2 += wv*wv; }
    dsc[tid] = fminf(1.0f, 1.0f / fmaxf(sqrtf(s2), 1e-7f));
  }
  if (tid >= 64 && tid < 96) {   // bnF folded scale/shift: 4 stages x 8 ch
    int i = tid - 64, s = i >> 3, f = i & 7;
    float g = ldin(bnF, s*32 + f,      isf32);
    float b = ldin(bnF, s*32 + 8 + f,  isf32);
    float m = ldin(bnF, s*32 + 16 + f, isf32);
    float v = ldin(bnF, s*32 + 24 + f, isf32);
    float sc = g * rsqrtf(v + 1e-3f);
    bnFs[s*16 + f] = sc; bnFs[s*16 + 8 + f] = b - m*sc;
  }
  if (tid >= 96 && tid < 112) {  // bn_sp
    int ch = tid - 96;
    float g = ldin(bnsp, ch, isf32), b = ldin(bnsp, 16 + ch, isf32);
    float m = ldin(bnsp, 32 + ch, isf32), v = ldin(bnsp, 48 + ch, isf32);
    float sc = g * rsqrtf(v + 1e-3f);
    bnsps[ch] = sc; bnsps[16 + ch] = b - m*sc;
  }
  if (tid >= 112 && tid < 128) { // bn_sep
    int ch = tid - 112;
    float g = ldin(bnsep, ch, isf32), b = ldin(bnsep, 16 + ch, isf32);
    float m = ldin(bnsep, 32 + ch, isf32), v = ldin(bnsep, 48 + ch, isf32);
    float sc = g * rsqrtf(v + 1e-3f);
    bnseps[ch] = sc; bnseps[16 + ch] = b - m*sc;
  }
  __syncthreads();
  for (int i = tid; i < 1024; i += 256) dwn[i] = dwr[i] * dsc[i >> 6];
  __syncthreads();
  // packed f16 dw-weight pairs (from shared dwr*dsc, no global dep)
  for (int idx = tid; idx < 512; idx += 256) {
    int ch = idx >> 5, p = idx & 31;
    dwph[idx] = pack2h(dwr[ch*64 + 2*p]   * dsc[ch],
                       dwr[ch*64 + 2*p+1] * dsc[ch]);
  }
}

// ---------------- K0b: avals + avph (parallel over 1536 combos) -----------
__global__ __launch_bounds__(256) void k0b_avals(
    const void* __restrict__ adj, const void* __restrict__ imp,
    const int* __restrict__ flag,
    const int* __restrict__ deg, const int* __restrict__ col,
    float* __restrict__ avals, unsigned int* __restrict__ avph)
{
  int combo = blockIdx.x * 256 + threadIdx.x;   // < 1536
  int isf32 = *flag;
  int c = combo & 63;
  int lf = combo >> 6;                 // l*8+f
  int dg = deg[c];
  float av[MAXDEG];
  for (int e = 0; e < MAXDEG; ++e) {
    float v = 0.0f;
    if (e < dg) {
      int d = col[c*MAXDEG + e];
      v = ldin(adj, c*64 + d, isf32) * ldin(imp, (lf*64 + c)*64 + d, isf32);
    }
    av[e] = v;
    avals[combo*MAXDEG + e] = v;
  }
  for (int p = 0; p < 8; ++p)
    avph[combo*8 + p] = pack2h(av[2*p], av[2*p + 1]);
}

// ---------------- K1: conv1 (64-tap) via MFMA + bn0 ------------------------
// grid (4 t-tiles of 1024, B*C). Stride-2 supertiles, duplicated B cols.
__global__ __launch_bounds__(256, 4) void k1_conv1_bn(
    const void* __restrict__ x,               // B,C,T raw dtype
    const uint4* __restrict__ w1mf,           // 2*64 B-fragments
    const float* __restrict__ bnFs,
    const int* __restrict__ flag,
    unsigned short* __restrict__ outp)        // B,F1,C,T f16
{
  __shared__ __align__(16) unsigned int xs[548];   // 1096 halfs
  int tid = threadIdx.x;
  int bc = blockIdx.y;                 // b*64+c
  int b = bc >> 6, c = bc & 63;
  int tb = blockIdx.x * 1024;
  int isf32 = *flag;
  int row = bc * T_;
  if (isf32) {
    const float* xr = (const float*)x + row;
    for (int m = tid; m < 274; m += 256) {
      int tg = tb - 36 + 4*m;
      uint2 st;
      if (tg >= 0 && tg + 3 < T_) {
        float4 v = *(const float4*)(xr + tg);               // 16B aligned
        st.x = pkh(v.x, v.y); st.y = pkh(v.z, v.w);
      } else {
        float q0 = (tg   >= 0 && tg   < T_) ? xr[tg]   : 0.0f;
        float q1 = (tg+1 >= 0 && tg+1 < T_) ? xr[tg+1] : 0.0f;
        float q2 = (tg+2 >= 0 && tg+2 < T_) ? xr[tg+2] : 0.0f;
        float q3 = (tg+3 >= 0 && tg+3 < T_) ? xr[tg+3] : 0.0f;
        st.x = pkh(q0, q1); st.y = pkh(q2, q3);
      }
      *(uint2*)(xs + 2*m) = st;
    }
  } else {
    const unsigned short* xr = (const unsigned short*)x + row;
    for (int m = tid; m < 274; m += 256) {
      int tg = tb - 36 + 4*m;
      uint2 st;
      if (tg >= 0 && tg + 3 < T_) {
        uint2 v = *(const uint2*)(xr + tg);                 // 8B aligned
        st.x = pkh(bf2f((unsigned short)(v.x & 0xFFFFu)),
                   bf2f((unsigned short)(v.x >> 16)));
        st.y = pkh(bf2f((unsigned short)(v.y & 0xFFFFu)),
                   bf2f((unsigned short)(v.y >> 16)));
      } else {
        float q0 = (tg   >= 0 && tg   < T_) ? bf2f(xr[tg])   : 0.0f;
        float q1 = (tg+1 >= 0 && tg+1 < T_) ? bf2f(xr[tg+1]) : 0.0f;
        float q2 = (tg+2 >= 0 && tg+2 < T_) ? bf2f(xr[tg+2]) : 0.0f;
        float q3 = (tg+3 >= 0 && tg+3 < T_) ? bf2f(xr[tg+3]) : 0.0f;
        st.x = pkh(q0, q1); st.y = pkh(q2, q3);
      }
      *(uint2*)(xs + 2*m) = st;
    }
  }
  __syncthreads();

  int lane = tid & 63;
  int wv4 = tid >> 6;                  // wave 0..3
  int m = lane & 15, q = lane >> 4;
  int sel = (m >> 3) & 1;              // 0: t+0..3, 1: t+4..7
  union { uint4 u; f16x8 h; } w0u, w1u;
  w0u.u = w1mf[lane];
  w1u.u = w1mf[64 + lane];
  int o8 = m & 7;
  float sc  = bnFs[o8];
  float shb = bnFs[8 + o8];
  const unsigned int* p0 = xs + 2 + m + 4*q + 128*wv4;
  unsigned short* orow = outp + (size_t)((b*8 + o8)*64 + c) * T_;
  #pragma unroll
  for (int s = 0; s < 8; ++s) {
    unsigned dwa[5], dwb[5];
    #pragma unroll
    for (int j = 0; j < 5; ++j) {
      dwa[j] = p0[16*s + j];           // kk=0 window
      dwb[j] = p0[16*s + 16 + j];      // kk=1 window (== s+1 kk=0: CSE)
    }
    union { unsigned d[4]; f16x8 h; } Ae0, Ao0, Ae1, Ao1;
    #pragma unroll
    for (int j = 0; j < 4; ++j) {
      Ao0.d[j] = dwa[j+1];                       // odd rows: pure copy
      Ae0.d[j] = alignb(dwa[j+1], dwa[j], 16);   // even rows: const shift
      Ao1.d[j] = dwb[j+1];
      Ae1.d[j] = alignb(dwb[j+1], dwb[j], 16);
    }
    f32x4 ae = {0.0f, 0.0f, 0.0f, 0.0f};
    f32x4 ao = {0.0f, 0.0f, 0.0f, 0.0f};
    ae = __builtin_amdgcn_mfma_f32_16x16x32_f16(Ae0.h, w0u.h, ae, 0, 0, 0);
    ae = __builtin_amdgcn_mfma_f32_16x16x32_f16(Ae1.h, w1u.h, ae, 0, 0, 0);
    ao = __builtin_amdgcn_mfma_f32_16x16x32_f16(Ao0.h, w0u.h, ao, 0, 0, 0);
    ao = __builtin_amdgcn_mfma_f32_16x16x32_f16(Ao1.h, w1u.h, ao, 0, 0, 0);
    // B cols duplicated: lane m>=8 owns D rows 4q+2,3 locally
    float y0 = sel ? ae[2] : ae[0];
    float y1 = sel ? ao[2] : ao[0];
    float y2 = sel ? ae[3] : ae[1];
    float y3 = sel ? ao[3] : ao[1];
    int t0g = tb + wv4*256 + s*32 + 8*q + 4*sel;
    if (t0g < T_) {
      uint2 st;
      st.x = pkh(y0*sc + shb, y1*sc + shb);
      st.y = pkh(y2*sc + shb, y3*sc + shb);
      *(uint2*)(orow + t0g) = st;
    }
  }
}

// ---------------- K23: fused graph einsum + MFMA gconv + bn + elu ----------
// grid (4, B*C), 256 thr, TILE=1024 (r22's 512 regressed — reverted).
// XCD swizzle: work = (c fastest, t-tile, b). Phase 1: 32 threads/i-row
// stage Ah into 16.6 KB LDS (edge-pair dot2, avph). Phase 2: 8 stride-2
// supertiles/wave; duplicated B cols -> swizzle-free epilogue.
__global__ __launch_bounds__(256, 6) void k23_gcn_gconv(
    const unsigned short* __restrict__ in,    // B,F1,C,T f16
    unsigned short* __restrict__ outp,        // B,F1,C,T f16
    const int* __restrict__ deg, const int* __restrict__ col,
    const float* __restrict__ avals,          // 3*8*64*MAXDEG (boundary path)
    const unsigned int* __restrict__ avph,    // 3*8*64*8 packed pairs
    const uint4* __restrict__ wmf,            // 6*64 B-fragments
    const float* __restrict__ bnFs, int l)
{
  __shared__ __align__(16) uint4 ash[8 * ROW4];   // 16,640 B
  int tid = threadIdx.x;
  // bijective XCD swizzle (8192 blocks, 8 XCDs)
  int wgid = blockIdx.y * 4 + blockIdx.x;
  int swz  = (wgid & 7) * 1024 + (wgid >> 3);
  int c = swz & 63;
  int xt = (swz >> 6) & 3;
  int b = swz >> 8;
  int tb = xt * 1024;
  int wb = tb - 8;                     // staged range [wb, wb+1040)
  int dg = deg[c];                     // uniform -> s_load
  const int* cp = col + c*MAXDEG;

  // ---- phase 1: stage Ah into LDS, 32 threads per i-row ----
  {
    int i = tid >> 5;                  // 0..7
    int mlane = tid & 31;
    int dgp = (dg + 1) >> 1;
    const unsigned int* wpp = avph + ((l*8 + i)*64 + c) * 8;   // uniform
    const float* av = avals + ((l*8 + i)*64 + c) * MAXDEG;     // uniform
    const unsigned short* rbp = in + (size_t)((b*8 + i) * 64) * T_;
    for (int m = mlane; m < ROW4; m += 32) {
      int t = wb + 8*m;
      float a[8] = {0,0,0,0,0,0,0,0};
      if (t >= 0 && t + 7 < T_) {
        for (int p = 0; p < dgp; ++p) {
          int d0 = cp[2*p];            // uniform -> s_load
          int d1 = cp[2*p + 1];
          h16x2 w2 = as_h2(wpp[p]);    // uniform
          uint4 v0 = *(const uint4*)(rbp + d0*T_ + t);   // 16B aligned
          uint4 v1 = *(const uint4*)(rbp + d1*T_ + t);
          a[0] = DOT2(as_h2(PERM_LO(v1.x, v0.x)), w2, a[0]);
          a[1] = DOT2(as_h2(PERM_HI(v1.x, v0.x)), w2, a[1]);
          a[2] = DOT2(as_h2(PERM_LO(v1.y, v0.y)), w2, a[2]);
          a[3] = DOT2(as_h2(PERM_HI(v1.y, v0.y)), w2, a[3]);
          a[4] = DOT2(as_h2(PERM_LO(v1.z, v0.z)), w2, a[4]);
          a[5] = DOT2(as_h2(PERM_HI(v1.z, v0.z)), w2, a[5]);
          a[6] = DOT2(as_h2(PERM_LO(v1.w, v0.w)), w2, a[6]);
          a[7] = DOT2(as_h2(PERM_HI(v1.w, v0.w)), w2, a[7]);
        }
      } else if (t + 7 >= 0 && t < T_) {
        for (int e = 0; e < dg; ++e) {
          int d = cp[e];
          float wv = av[e];
          const unsigned short* rp = rbp + d*T_;
          #pragma unroll
          for (int q = 0; q < 8; ++q) {
            int tq = t + q;
            if (tq >= 0 && tq < T_)
              a[q] = fmaf(wv, lo_h((unsigned int)rp[tq]), a[q]);
          }
        }
      }
      uint4 o;
      o.x = pkh(a[0], a[1]); o.y = pkh(a[2], a[3]);
      o.z = pkh(a[4], a[5]); o.w = pkh(a[6], a[7]);
      ash[i*ROW4 + m] = o;
    }
  }
  __syncthreads();

  // ---- phase 2: MFMA gconv, 8 stride-2 supertiles/wave ----
  int lane = tid & 63;
  int wv4 = tid >> 6;                  // wave 0..3
  int m = lane & 15, q = lane >> 4;
  int sel = (m >> 3) & 1;              // 0: t+0..3, 1: t+4..7
  union { uint4 u; f16x8 h; } w0u, w1u;
  w0u.u = wmf[(l*2 + 0)*64 + lane];
  w1u.u = wmf[(l*2 + 1)*64 + lane];
  int o8 = m & 7;
  float sc  = bnFs[(l+1)*16 + o8];
  float shb = bnFs[(l+1)*16 + 8 + o8];
  const unsigned int* ashd = (const unsigned int*)ash;
  const unsigned int* p0 = ashd + q*ROWD + wv4*128 + m + 2;   // dword idx
  const unsigned int* p1 = p0 + 4*ROWD;
  unsigned short* orow = outp + (size_t)((b*8 + o8)*64 + c) * T_;
  #pragma unroll
  for (int s = 0; s < 8; ++s) {
    unsigned dwa[5], dwb[5];
    #pragma unroll
    for (int j = 0; j < 5; ++j) {      // immediate-offset ds_read2_b32
      dwa[j] = p0[16*s + j];
      dwb[j] = p1[16*s + j];
    }
    union { unsigned d[4]; f16x8 h; } Ae0, Ao0, Ae1, Ao1;
    #pragma unroll
    for (int j = 0; j < 4; ++j) {
      Ao0.d[j] = dwa[j+1];                       // odd rows: pure copy
      Ae0.d[j] = alignb(dwa[j+1], dwa[j], 16);   // even rows: const shift
      Ao1.d[j] = dwb[j+1];
      Ae1.d[j] = alignb(dwb[j+1], dwb[j], 16);
    }
    f32x4 ae = {0.0f, 0.0f, 0.0f, 0.0f};
    f32x4 ao = {0.0f, 0.0f, 0.0f, 0.0f};
    ae = __builtin_amdgcn_mfma_f32_16x16x32_f16(Ae0.h, w0u.h, ae, 0, 0, 0);
    ae = __builtin_amdgcn_mfma_f32_16x16x32_f16(Ae1.h, w1u.h, ae, 0, 0, 0);
    ao = __builtin_amdgcn_mfma_f32_16x16x32_f16(Ao0.h, w0u.h, ao, 0, 0, 0);
    ao = __builtin_amdgcn_mfma_f32_16x16x32_f16(Ao1.h, w1u.h, ao, 0, 0, 0);
    // B cols duplicated: lane m>=8 owns D rows 4q+2,3 locally
    float y0 = sel ? ae[2] : ae[0];
    float y1 = sel ? ao[2] : ao[0];
    float y2 = sel ? ae[3] : ae[1];
    float y3 = sel ? ao[3] : ao[1];
    int t0g = tb + wv4*256 + s*32 + 8*q + 4*sel;
    if (t0g < T_) {
      uint2 st;
      st.x = pkh(eluf(y0*sc + shb), eluf(y1*sc + shb));
      st.y = pkh(eluf(y2*sc + shb), eluf(y3*sc + shb));
      *(uint2*)(orow + t0g) = st;
    }
  }
}

// ---------------- K4: depthwise-over-C + bn + elu + avgpool4. 8 t/thread ---
// cc-pair dot2: (h_cc0[t],h_cc1[t]) via v_perm, weight pairs dwph (SGPR).
__global__ __launch_bounds__(256) void k4_dw(
    const unsigned short* __restrict__ in,    // B,F1,C,T f16
    const unsigned int* __restrict__ dwph,    // 16x32 packed f16 pairs
    const float* __restrict__ bnsps,
    float* __restrict__ p1)                   // B,16,1000 fp32
{
  int tid = threadIdx.x;
  int bg = blockIdx.y;                 // b*8+g
  int b = bg >> 3, g = bg & 7;
  int tile = blockIdx.x * 256 + tid;
  if (tile >= 500) return;
  int t0 = tile * 8;
  int base = bg * (64 * T_);
  const unsigned int* w0pp = dwph + (2*g)*32;      // uniform -> s_load
  const unsigned int* w1pp = dwph + (2*g + 1)*32;
  float a0[8] = {0,0,0,0,0,0,0,0}, a1[8] = {0,0,0,0,0,0,0,0};
  for (int p = 0; p < 32; ++p) {
    h16x2 w02 = as_h2(w0pp[p]);        // uniform
    h16x2 w12 = as_h2(w1pp[p]);        // uniform
    uint4 v0 = *(const uint4*)(in + base + (2*p)*T_ + t0);
    uint4 v1 = *(const uint4*)(in + base + (2*p + 1)*T_ + t0);
    unsigned pr;
    pr = PERM_LO(v1.x, v0.x);
    a0[0] = DOT2(as_h2(pr), w02, a0[0]); a1[0] = DOT2(as_h2(pr), w12, a1[0]);
    pr = PERM_HI(v1.x, v0.x);
    a0[1] = DOT2(as_h2(pr), w02, a0[1]); a1[1] = DOT2(as_h2(pr), w12, a1[1]);
    pr = PERM_LO(v1.y, v0.y);
    a0[2] = DOT2(as_h2(pr), w02, a0[2]); a1[2] = DOT2(as_h2(pr), w12, a1[2]);
    pr = PERM_HI(v1.y, v0.y);
    a0[3] = DOT2(as_h2(pr), w02, a0[3]); a1[3] = DOT2(as_h2(pr), w12, a1[3]);
    pr = PERM_LO(v1.z, v0.z);
    a0[4] = DOT2(as_h2(pr), w02, a0[4]); a1[4] = DOT2(as_h2(pr), w12, a1[4]);
    pr = PERM_HI(v1.z, v0.z);
    a0[5] = DOT2(as_h2(pr), w02, a0[5]); a1[5] = DOT2(as_h2(pr), w12, a1[5]);
    pr = PERM_LO(v1.w, v0.w);
    a0[6] = DOT2(as_h2(pr), w02, a0[6]); a1[6] = DOT2(as_h2(pr), w12, a1[6]);
    pr = PERM_HI(v1.w, v0.w);
    a0[7] = DOT2(as_h2(pr), w02, a0[7]); a1[7] = DOT2(as_h2(pr), w12, a1[7]);
  }
  float sc0 = bnsps[2*g],     sh0 = bnsps[16 + 2*g];
  float sc1 = bnsps[2*g + 1], sh1 = bnsps[16 + 2*g + 1];
  int oi = t0 >> 2;
  float2 r0, r1;
  r0.x = 0.25f * (eluf(a0[0]*sc0+sh0) + eluf(a0[1]*sc0+sh0)
                + eluf(a0[2]*sc0+sh0) + eluf(a0[3]*sc0+sh0));
  r0.y = 0.25f * (eluf(a0[4]*sc0+sh0) + eluf(a0[5]*sc0+sh0)
                + eluf(a0[6]*sc0+sh0) + eluf(a0[7]*sc0+sh0));
  r1.x = 0.25f * (eluf(a1[0]*sc1+sh1) + eluf(a1[1]*sc1+sh1)
                + eluf(a1[2]*sc1+sh1) + eluf(a1[3]*sc1+sh1));
  r1.y = 0.25f * (eluf(a1[4]*sc1+sh1) + eluf(a1[5]*sc1+sh1)
                + eluf(a1[6]*sc1+sh1) + eluf(a1[7]*sc1+sh1));
  *(float2*)(p1 + (b*16 + 2*g)*TP_ + oi)     = r0;
  *(float2*)(p1 + (b*16 + 2*g + 1)*TP_ + oi) = r1;
}

// ---------------- K5: sep dw(16) + pw(16x16) + bn + elu + pool8 + fc -------
// grid (4, B). Block covers w0 [wq*256, wq*256+256) = 32 aligned pool-8
// groups; pooled j = wq*32 + g (valid j < 125). feature = ch*125 + j.
// Partial fc sums block-reduced then 4 atomicAdds into fcacc[b*4+n].
// p2 never materialized. No early return before barriers.
__global__ __launch_bounds__(256) void k5_sep_fc(
    const float* __restrict__ p1,             // B,16,1000
    const float* __restrict__ sdwc,           // 16x16 (uniform)
    const float* __restrict__ pwc,            // 16x16 (uniform)
    const float* __restrict__ bnseps,
    const float* __restrict__ fcwc,           // 4x2000 (uniform)
    float* __restrict__ fcacc)                // B*4 f32
{
  __shared__ float ps[16*272];
  __shared__ float vals[16*256];
  __shared__ float red[4*64];
  int tid = threadIdx.x;
  int wq = blockIdx.x, b = blockIdx.y;
  int wb = wq * 256;
  for (int ch = 0; ch < 16; ++ch) {
    for (int s = tid; s < 272; s += 256) {
      int t = wb - 8 + s;
      ps[ch*272 + s] = (t >= 0 && t < TP_) ? p1[(b*16 + ch)*TP_ + t] : 0.0f;
    }
  }
  __syncthreads();
  int w0 = wb + tid;
  bool valid = (w0 < TP_);             // pooling uses only w < 1000
  float dws[16];
  for (int ch = 0; ch < 16; ++ch) {
    float a = 0.0f;
    #pragma unroll
    for (int k = 0; k < 16; ++k)
      a = fmaf(sdwc[ch*16 + k], ps[ch*272 + tid + k], a);
    dws[ch] = a;
  }
  for (int f = 0; f < 16; ++f) {
    float a = 0.0f;
    #pragma unroll
    for (int ch = 0; ch < 16; ++ch) a = fmaf(pwc[f*16 + ch], dws[ch], a);
    float sc = bnseps[f], sh = bnseps[16 + f];
    vals[f*256 + tid] = valid ? eluf(a*sc + sh) : 0.0f;
  }
  __syncthreads();
  float part[4] = {0.0f, 0.0f, 0.0f, 0.0f};
  #pragma unroll
  for (int it = 0; it < 2; ++it) {
    int item = it*256 + tid;           // (ch, g): ch = item>>5, g = item&31
    int ch = item >> 5, g = item & 31;
    int j = wq*32 + g;
    if (j < 125) {
      const float* vp = vals + ch*256 + 8*g;
      float s8 = vp[0]+vp[1]+vp[2]+vp[3]+vp[4]+vp[5]+vp[6]+vp[7];
      float mval = 0.125f * s8;
      int fi = ch*125 + j;
      #pragma unroll
      for (int n = 0; n < 4; ++n)
        part[n] = fmaf(fcwc[n*2000 + fi], mval, part[n]);
    }
  }
  // wave reduce (64 lanes) then LDS reduce across 4 waves
  #pragma unroll
  for (int n = 0; n < 4; ++n) {
    float v = part[n];
    for (int off = 32; off > 0; off >>= 1) v += __shfl_down(v, off, 64);
    if ((tid & 63) == 0) red[n*64 + (tid >> 6)] = v;
  }
  __syncthreads();
  if (tid < 4) {
    float v = red[tid*64 + 0] + red[tid*64 + 1]
            + red[tid*64 + 2] + red[tid*64 + 3];
    atomicAdd(&fcacc[b*4 + tid], v);
  }
}

// ---------------- K6c: bias + convert (1 block) ----------------------------
__global__ __launch_bounds__(128) void k6c_out(
    const float* __restrict__ fcacc, const float* __restrict__ fcbc,
    const int* __restrict__ flag, void* __restrict__ outp)
{
  int tid = threadIdx.x;               // 0..127 = b*4+n
  float val = fcacc[tid] + fcbc[tid & 3];
  if (*flag) ((float*)outp)[tid] = val;
  else       ((unsigned short*)outp)[tid] = f2bf(val);
}

// ---------------------------------------------------------------------------
extern "C" void kernel_launch(void* const* d_in, const int* in_sizes, int n_in,
                              void* d_out, int out_size, void* d_ws, size_t ws_size,
                              hipStream_t stream) {
  const void* x     = d_in[0];
  const void* adj   = d_in[1];
  const void* w1    = d_in[2];
  const void* bnF   = d_in[3];
  const void* imp   = d_in[4];
  const void* gw    = d_in[5];
  const void* dww   = d_in[6];
  const void* bnsp  = d_in[7];
  const void* sdw   = d_in[8];
  const void* pw    = d_in[9];
  const void* bnsep = d_in[10];
  const void* fcw   = d_in[11];
  const void* fcb   = d_in[12];

  char* w = (char*)d_ws;
  const size_t OFF = 262144000;  // after two 131,072,000-byte f16 buffers
  unsigned short* bufA = (unsigned short*)(w);
  unsigned short* bufB = (unsigned short*)(w + 131072000);
  int*   flag   = (int*)  (w + OFF + 0);
  int*   deg    = (int*)  (w + OFF + 256);
  int*   col    = (int*)  (w + OFF + 512);
  float* avals  = (float*)(w + OFF + 4608);
  float* dwn    = (float*)(w + OFF + 108032);
  float* sdwc   = (float*)(w + OFF + 112128);
  float* pwc    = (float*)(w + OFF + 113152);
  float* fcwc   = (float*)(w + OFF + 114176);
  float* fcbc   = (float*)(w + OFF + 146176);
  float* bnFs   = (float*)(w + OFF + 146432);
  float* bnsps  = (float*)(w + OFF + 146688);
  float* bnseps = (float*)(w + OFF + 146944);
  float* p1     = (float*)(w + OFF + 147200);
  uint4* wmf    = (uint4*)(w + OFF + 4245248);              // 384 uint4
  unsigned int* avph = (unsigned int*)(w + OFF + 4251392);  // 12288 uints
  unsigned int* dwph = (unsigned int*)(w + OFF + 4300544);  // 512 uints
  uint4* w1mf   = (uint4*)(w + OFF + 4302592);              // 128 uint4
  float* fcacc  = (float*)(w + OFF + 4304640);              // 128 f32

  k0_setup<<<1, 256, 0, stream>>>(adj, imp, dww, w1, bnF, gw, bnsp, sdw, pw,
                                  bnsep, fcw, fcb, flag, deg, col,
                                  w1mf, wmf, dwn, sdwc, pwc, fcwc, fcbc,
                                  bnFs, bnsps, bnseps, dwph, fcacc);
  k0b_avals<<<6, 256, 0, stream>>>(adj, imp, flag, deg, col, avals, avph);
  k1_conv1_bn<<<dim3(4, B_*C_), 256, 0, stream>>>(x, w1mf, bnFs, flag, bufA);
  for (int l = 0; l < 3; ++l) {
    const unsigned short* src = (l & 1) ? bufB : bufA;
    unsigned short*       dst = (l & 1) ? bufA : bufB;
    k23_gcn_gconv<<<dim3(4, B_*C_), 256, 0, stream>>>(src, dst, deg, col,
                                                      avals, avph, wmf, bnFs, l);
  }
  k4_dw<<<dim3(2, B_*F1_), 256, 0, stream>>>(bufB, dwph, bnsps, p1);
  k5_sep_fc<<<dim3(4, B_), 256, 0, stream>>>(p1, sdwc, pwc, bnseps,
                                             fcwc, fcacc);
  k6c_out<<<1, 128, 0, stream>>>(fcacc, fcbc, flag, d_out);
}